// Round 7
// baseline (42102.054 us; speedup 1.0000x reference)
//
#include <hip/hip_runtime.h>
#include <math.h>

typedef __attribute__((ext_vector_type(8))) short short8;
typedef __attribute__((ext_vector_type(4))) float f32x4;

constexpr int NV = 50000;    // V
constexpr int NL = 100000;   // 2V literal rows
constexpr int NC = 200000;   // clauses
constexpr int NE = 300000;   // edges per polarity
constexpr int NROUNDS = 26;

__device__ __forceinline__ float sigf(float x) { return 1.0f / (1.0f + expf(-x)); }

// in-register f32 -> bf16 hi/lo split (truncation; combined rel err ~2^-16)
__device__ __forceinline__ void split8(const float* a, short8& h, short8& l) {
#pragma unroll
    for (int j = 0; j < 8; j++) {
        unsigned u = __float_as_uint(a[j]);
        h[j] = (short)(u >> 16);
        float lf = a[j] - __uint_as_float(u & 0xffff0000u);
        l[j] = (short)(__float_as_uint(lf) >> 16);
    }
}

// weight split with RTN on both halves (one-time prep)
__device__ __forceinline__ void splitw(float x, unsigned short* h, unsigned short* l) {
    unsigned u = __float_as_uint(x);
    unsigned hr = (u + 0x7fffu + ((u >> 16) & 1u)) & 0xffff0000u;
    float lf = x - __uint_as_float(hr);
    unsigned ul = __float_as_uint(lf);
    *h = (unsigned short)(hr >> 16);
    *l = (unsigned short)((ul + 0x7fffu + ((ul >> 16) & 1u)) >> 16);
}

// ======== weight prep: fragment-major packed layouts ========
// frag id: (((kt*NT + tile)*64 + lane)*8 + j); elem = W^T[n = tile*16 + (lane&15)][k = kt*32 + (lane>>4)*8 + j]

__global__ __launch_bounds__(256) void pack_mlp_frag(
    const float* __restrict__ W, unsigned short* __restrict__ Wh, unsigned short* __restrict__ Wl)
{
    int fid = blockIdx.x * 256 + threadIdx.x;   // 3*4*8*64 = 6144
    if (fid >= 6144) return;
    int lane = fid & 63;
    int tile = (fid >> 6) & 7;
    int kt = (fid >> 9) & 3;
    int layer = fid >> 11;
    int l15 = lane & 15, lg = lane >> 4;
    int n = tile * 16 + l15;
#pragma unroll
    for (int j = 0; j < 8; j++) {
        int k = kt * 32 + lg * 8 + j;
        unsigned short h, l;
        splitw(W[layer * 16384 + k * 128 + n], &h, &l);
        Wh[(size_t)fid * 8 + j] = h;
        Wl[(size_t)fid * 8 + j] = l;
    }
}

__global__ __launch_bounds__(256) void pack_lstm_frag(
    const float* __restrict__ Wih, const float* __restrict__ Whh, int kih, int nstep,
    unsigned short* __restrict__ Wh, unsigned short* __restrict__ Wl)
{
    int fid = blockIdx.x * 256 + threadIdx.x;   // nstep*32*64
    if (fid >= nstep * 2048) return;
    int lane = fid & 63;
    int tile = (fid >> 6) & 31;
    int kt = fid >> 11;
    int l15 = lane & 15, lg = lane >> 4;
    int n = tile * 16 + l15;
#pragma unroll
    for (int j = 0; j < 8; j++) {
        int k = kt * 32 + lg * 8 + j;
        float v = (k < kih) ? Wih[n * kih + k] : Whh[(n << 7) + (k - kih)];
        unsigned short h, l;
        splitw(v, &h, &l);
        Wh[(size_t)fid * 8 + j] = h;
        Wl[(size_t)fid * 8 + j] = l;
    }
}

// ================= CSR build (once per call) =================
__global__ __launch_bounds__(256) void csr_hist_k(
    const int* __restrict__ ps, const int* __restrict__ pd,
    const int* __restrict__ ns, const int* __restrict__ nd,
    int* __restrict__ cnt_c, int* __restrict__ cnt_l)
{
    int e = blockIdx.x * 256 + threadIdx.x;
    if (e >= NE) return;
    atomicAdd(&cnt_c[pd[e]], 1);
    atomicAdd(&cnt_c[nd[e]], 1);
    atomicAdd(&cnt_l[ps[e]], 1);
    atomicAdd(&cnt_l[NV + ns[e]], 1);
}

__global__ __launch_bounds__(256) void scan_p1(
    const int* __restrict__ cnt, int* __restrict__ partials, int n)
{
    __shared__ int sdata[256];
    int t = threadIdx.x, b = blockIdx.x;
    int base = b * 1024 + t * 4;
    int s = 0;
#pragma unroll
    for (int j = 0; j < 4; j++) { int i = base + j; if (i < n) s += cnt[i]; }
    sdata[t] = s; __syncthreads();
    for (int st = 128; st > 0; st >>= 1) {
        if (t < st) sdata[t] += sdata[t + st];
        __syncthreads();
    }
    if (t == 0) partials[b] = sdata[0];
}

__global__ __launch_bounds__(256) void scan_p2(int* __restrict__ partials, int nb, int* __restrict__ rowptr_end)
{
    __shared__ int sdata[256];
    int t = threadIdx.x;
    int v = (t < nb) ? partials[t] : 0;
    int x = v;
    sdata[t] = x; __syncthreads();
    for (int st = 1; st < 256; st <<= 1) {
        int y = (t >= st) ? sdata[t - st] : 0;
        __syncthreads();
        x += y; sdata[t] = x;
        __syncthreads();
    }
    if (t < nb) partials[t] = x - v;
    if (t == 255) *rowptr_end = sdata[255];
}

__global__ __launch_bounds__(256) void scan_p3(
    const int* __restrict__ cnt, const int* __restrict__ partials,
    int* __restrict__ rowptr, int* __restrict__ cursor, int n)
{
    __shared__ int sdata[256];
    int t = threadIdx.x, b = blockIdx.x;
    int base = b * 1024 + t * 4;
    int v[4]; int s = 0;
#pragma unroll
    for (int j = 0; j < 4; j++) { int i = base + j; v[j] = (i < n) ? cnt[i] : 0; s += v[j]; }
    int x = s;
    sdata[t] = x; __syncthreads();
    for (int st = 1; st < 256; st <<= 1) {
        int y = (t >= st) ? sdata[t - st] : 0;
        __syncthreads();
        x += y; sdata[t] = x;
        __syncthreads();
    }
    int off = partials[b] + x - s;
#pragma unroll
    for (int j = 0; j < 4; j++) {
        int i = base + j;
        if (i < n) { rowptr[i] = off; cursor[i] = off; off += v[j]; }
    }
}

__global__ __launch_bounds__(256) void csr_fill_k(
    const int* __restrict__ ps, const int* __restrict__ pd,
    const int* __restrict__ ns, const int* __restrict__ nd,
    int* __restrict__ cur_c, int* __restrict__ eidx_c,
    int* __restrict__ cur_l, int* __restrict__ eidx_l)
{
    int e = blockIdx.x * 256 + threadIdx.x;
    if (e >= NE) return;
    int p;
    p = atomicAdd(&cur_c[pd[e]], 1); eidx_c[p] = ps[e];
    p = atomicAdd(&cur_c[nd[e]], 1); eidx_c[p] = NV + ns[e];
    p = atomicAdd(&cur_l[ps[e]], 1); eidx_l[p] = pd[e];
    p = atomicAdd(&cur_l[NV + ns[e]], 1); eidx_l[p] = nd[e];
}

// ---- gather-sum: out[row] = sum msg[eidx[j]] ; one wave per row ----
__global__ __launch_bounds__(256) void gather_sum_k(
    const float* __restrict__ msg, const int* __restrict__ rowptr,
    const int* __restrict__ eidx, float* __restrict__ out, int nrows)
{
    int row = (blockIdx.x * 256 + threadIdx.x) >> 6;
    if (row >= nrows) return;
    int lane = threadIdx.x & 63;
    int beg = rowptr[row], end = rowptr[row + 1];
    float ax = 0.f, ay = 0.f;
    for (int j = beg; j < end; j++) {
        int src = eidx[j];
        float2 v = *reinterpret_cast<const float2*>(msg + (size_t)src * 128 + lane * 2);
        ax += v.x; ay += v.y;
    }
    *reinterpret_cast<float2*>(out + (size_t)row * 128 + lane * 2) = make_float2(ax, ay);
}

// ---------------- fused 3-layer MLP: BM=128, LDS activation bounce, B frags from L2 ----------------
__global__ __launch_bounds__(256, 2) void mlp3_v3(
    const float* __restrict__ x, const unsigned short* __restrict__ Wh,
    const unsigned short* __restrict__ Wl, const float* __restrict__ bias,
    float* __restrict__ y, int M)
{
    __shared__ float Xs[128][132];
    const int t = threadIdx.x;
    const int rb = blockIdx.x * 128;
    const int lane = t & 63, w = t >> 6, wr = w >> 1, wc = w & 1;
    const int l15 = lane & 15, lg = lane >> 4;

#pragma unroll
    for (int j = 0; j < 16; j++) {
        int i = t + 256 * j;
        int r = i >> 5, c4 = i & 31;
        int gr = rb + r; if (gr >= M) gr = M - 1;
        *reinterpret_cast<float4*>(&Xs[r][c4 * 4]) =
            *reinterpret_cast<const float4*>(x + (size_t)gr * 128 + c4 * 4);
    }
    __syncthreads();

    for (int layer = 0; layer < 3; layer++) {
        f32x4 acc[4][4];
#pragma unroll
        for (int m = 0; m < 4; m++)
#pragma unroll
            for (int nf = 0; nf < 4; nf++) acc[m][nf] = f32x4{0.f, 0.f, 0.f, 0.f};

#pragma unroll
        for (int kt = 0; kt < 4; kt++) {
            short8 ah[4], al[4];
#pragma unroll
            for (int m = 0; m < 4; m++) {
                int row = wr * 64 + m * 16 + l15;
                float av[8];
                *reinterpret_cast<float4*>(&av[0]) =
                    *reinterpret_cast<const float4*>(&Xs[row][kt * 32 + lg * 8]);
                *reinterpret_cast<float4*>(&av[4]) =
                    *reinterpret_cast<const float4*>(&Xs[row][kt * 32 + lg * 8 + 4]);
                split8(av, ah[m], al[m]);
            }
#pragma unroll
            for (int nf = 0; nf < 4; nf++) {
                int tile = wc * 4 + nf;
                size_t off = ((size_t)(((layer * 4 + kt) * 8) + tile) * 64 + lane) * 8;
                short8 bh = *reinterpret_cast<const short8*>(Wh + off);
                short8 bl = *reinterpret_cast<const short8*>(Wl + off);
#pragma unroll
                for (int m = 0; m < 4; m++) {
                    acc[m][nf] = __builtin_amdgcn_mfma_f32_16x16x32_bf16(ah[m], bh, acc[m][nf], 0, 0, 0);
                    acc[m][nf] = __builtin_amdgcn_mfma_f32_16x16x32_bf16(ah[m], bl, acc[m][nf], 0, 0, 0);
                    acc[m][nf] = __builtin_amdgcn_mfma_f32_16x16x32_bf16(al[m], bh, acc[m][nf], 0, 0, 0);
                }
            }
        }
        float bv[4];
#pragma unroll
        for (int nf = 0; nf < 4; nf++) bv[nf] = bias[layer * 128 + wc * 64 + nf * 16 + l15];
        __syncthreads();
        if (layer < 2) {
#pragma unroll
            for (int m = 0; m < 4; m++)
#pragma unroll
                for (int nf = 0; nf < 4; nf++)
#pragma unroll
                    for (int rr = 0; rr < 4; rr++) {
                        float v = fmaxf(acc[m][nf][rr] + bv[nf], 0.f);
                        Xs[wr * 64 + m * 16 + lg * 4 + rr][wc * 64 + nf * 16 + l15] = v;
                    }
            __syncthreads();
        } else {
#pragma unroll
            for (int m = 0; m < 4; m++)
#pragma unroll
                for (int rr = 0; rr < 4; rr++) {
                    int gr = rb + wr * 64 + m * 16 + lg * 4 + rr;
                    if (gr < M) {
#pragma unroll
                        for (int nf = 0; nf < 4; nf++)
                            y[(size_t)gr * 128 + wc * 64 + nf * 16 + l15] = acc[m][nf][rr] + bv[nf];
                    }
                }
        }
    }
}

// ---------------- LSTM v3: N-sliced, B-slice resident in LDS, barrier-free row loop ----------------
// grid (4 slices, 256); block 256 thr (4 waves). Block tile: 128 rows x (32 colc x 4 gates).
// Wave: 64 rows (wr) x 16 colc (wc) x 4 gates. acc[4 m][4 g].
// LDS: 8 kt x 8 lt x 2 sel x 64 lanes x 16B = 128 KB, staged once, read-only after.
template <int NKT, bool FLIP>
__global__ __launch_bounds__(256, 1) void lstm_v3(
    const float* __restrict__ A0, const float* __restrict__ A1, const float* __restrict__ A2,
    const unsigned short* __restrict__ Bh_g, const unsigned short* __restrict__ Bl_g,
    const float* __restrict__ bih, const float* __restrict__ bhh,
    float* __restrict__ c_st, float* __restrict__ h_out, int M)
{
    constexpr int NKT_LDS = 8;   // kts 0..7 (K<256) from LDS; rest from global frags
    __shared__ unsigned short Bs[NKT_LDS * 8 * 2 * 512];   // 131072 B
    const int t = threadIdx.x;
    const int s = blockIdx.x;            // N-slice 0..3
    const int lane = t & 63, w = t >> 6, wr = w >> 1, wc = w & 1;
    const int l15 = lane & 15, lg = lane >> 4;

    // ---- stage B slice: tiles {g*8 + s*2 + j} for g<4, j<2 ----
#pragma unroll
    for (int it = 0; it < 32; it++) {
        int idx = t + 256 * it;          // = ((kt*8+lt)*2+sel)*64 + lane
        int ln = idx & 63;
        int sel = (idx >> 6) & 1;
        int lt = (idx >> 7) & 7;
        int kt = idx >> 10;
        int gtile = (lt >> 1) * 8 + s * 2 + (lt & 1);
        const unsigned short* src = sel ? Bl_g : Bh_g;
        size_t fid = ((size_t)(kt * 32 + gtile) * 64 + ln) * 8;
        *reinterpret_cast<uint4*>(&Bs[(size_t)idx * 8]) =
            *reinterpret_cast<const uint4*>(src + fid);
    }
    __syncthreads();   // only barrier; Bs is read-only afterwards

    const int colc = s * 32 + wc * 16 + l15;   // column within a gate block [0,128)
    float bs4[4];
#pragma unroll
    for (int g = 0; g < 4; g++) bs4[g] = bih[g * 128 + colc] + bhh[g * 128 + colc];

    const int ntiles = (M + 127) >> 7;
    for (int tile = blockIdx.y; tile < ntiles; tile += gridDim.y) {
        const int rowbase = tile << 7;
        int r0[4], rF[4];
#pragma unroll
        for (int m = 0; m < 4; m++) {
            int r = rowbase + wr * 64 + m * 16 + l15;
            if (r >= M) r = M - 1;
            r0[m] = r;
            rF[m] = FLIP ? ((r < NV) ? r + NV : r - NV) : r;
        }

        f32x4 acc[4][4];
#pragma unroll
        for (int m = 0; m < 4; m++)
#pragma unroll
            for (int g = 0; g < 4; g++) acc[m][g] = f32x4{0.f, 0.f, 0.f, 0.f};

        // prefetch kt=0 A
        float4 avc[4][2];
        {
            const float* src = A0;
#pragma unroll
            for (int m = 0; m < 4; m++) {
                const float* p = src + (size_t)r0[m] * 128 + lg * 8;
                avc[m][0] = *reinterpret_cast<const float4*>(p);
                avc[m][1] = *reinterpret_cast<const float4*>(p + 4);
            }
        }

#pragma unroll
        for (int kt = 0; kt < NKT; kt++) {
            // prefetch kt+1 A
            float4 avn[4][2];
            if (kt + 1 < NKT) {
                const int seg = (kt + 1) >> 2;
                const float* src = (seg == 0) ? A0 : ((seg == 1) ? A1 : A2);
                const bool useF = FLIP && (seg == 1);
                const int kcol = ((kt + 1) & 3) * 32 + lg * 8;
#pragma unroll
                for (int m = 0; m < 4; m++) {
                    const float* p = src + (size_t)(useF ? rF[m] : r0[m]) * 128 + kcol;
                    avn[m][0] = *reinterpret_cast<const float4*>(p);
                    avn[m][1] = *reinterpret_cast<const float4*>(p + 4);
                }
            }
            // split current A
            short8 ah[4], al[4];
#pragma unroll
            for (int m = 0; m < 4; m++) {
                float av[8];
                *reinterpret_cast<float4*>(&av[0]) = avc[m][0];
                *reinterpret_cast<float4*>(&av[4]) = avc[m][1];
                split8(av, ah[m], al[m]);
            }
            // B frags + MFMA
#pragma unroll
            for (int g = 0; g < 4; g++) {
                short8 bh, bl;
                if (kt < NKT_LDS) {
                    int uidx = ((kt * 8 + g * 2 + wc) * 2) * 64 + lane;
                    bh = *reinterpret_cast<const short8*>(&Bs[(size_t)uidx * 8]);
                    bl = *reinterpret_cast<const short8*>(&Bs[(size_t)(uidx + 64) * 8]);
                } else {
                    int gtile = g * 8 + s * 2 + wc;
                    size_t fid = ((size_t)(kt * 32 + gtile) * 64 + lane) * 8;
                    bh = *reinterpret_cast<const short8*>(Bh_g + fid);
                    bl = *reinterpret_cast<const short8*>(Bl_g + fid);
                }
#pragma unroll
                for (int m = 0; m < 4; m++) {
                    acc[m][g] = __builtin_amdgcn_mfma_f32_16x16x32_bf16(ah[m], bh, acc[m][g], 0, 0, 0);
                    acc[m][g] = __builtin_amdgcn_mfma_f32_16x16x32_bf16(ah[m], bl, acc[m][g], 0, 0, 0);
                    acc[m][g] = __builtin_amdgcn_mfma_f32_16x16x32_bf16(al[m], bh, acc[m][g], 0, 0, 0);
                }
            }
#pragma unroll
            for (int m = 0; m < 4; m++) { avc[m][0] = avn[m][0]; avc[m][1] = avn[m][1]; }
        }

        // epilogue: bias + activations + state update (cols owned exclusively by this thread)
#pragma unroll
        for (int m = 0; m < 4; m++)
#pragma unroll
            for (int rr = 0; rr < 4; rr++) {
                int gr = rowbase + wr * 64 + m * 16 + lg * 4 + rr;
                if (gr >= M) continue;
                float gi = acc[m][0][rr] + bs4[0];
                float gf = acc[m][1][rr] + bs4[1];
                float gg = acc[m][2][rr] + bs4[2];
                float go = acc[m][3][rr] + bs4[3];
                size_t p = (size_t)gr * 128 + colc;
                float cold = c_st[p];
                float cn = sigf(gf) * cold + sigf(gi) * tanhf(gg);
                float hn = sigf(go) * tanhf(cn);
                c_st[p] = cn;
                h_out[p] = hn;
            }
    }
}

extern "C" void kernel_launch(void* const* d_in, const int* in_sizes, int n_in,
                              void* d_out, int out_size, void* d_ws, size_t ws_size,
                              hipStream_t stream)
{
    const float* l_pos   = (const float*)d_in[0];
    const float* l_neg   = (const float*)d_in[1];
    const float* c_emb   = (const float*)d_in[2];
    const float* l_mlp_W = (const float*)d_in[3];
    const float* l_mlp_b = (const float*)d_in[4];
    const float* c_mlp_W = (const float*)d_in[5];
    const float* c_mlp_b = (const float*)d_in[6];
    const float* l_Wih   = (const float*)d_in[7];
    const float* l_Whh   = (const float*)d_in[8];
    const float* l_bih   = (const float*)d_in[9];
    const float* l_bhh   = (const float*)d_in[10];
    const float* c_Wih   = (const float*)d_in[11];
    const float* c_Whh   = (const float*)d_in[12];
    const float* c_bih   = (const float*)d_in[13];
    const float* c_bhh   = (const float*)d_in[14];
    const int* pos_src   = (const int*)d_in[15];
    const int* pos_dst   = (const int*)d_in[16];
    const int* neg_src   = (const int*)d_in[17];
    const int* neg_dst   = (const int*)d_in[18];

    float* out  = (float*)d_out;
    float* l_hA = out;
    float* c_hP = out + (size_t)NL * 128;     // clause-h ping (final resting place)

    float* wsp = (float*)d_ws;
    float* l_hB  = wsp; wsp += (size_t)NL * 128;
    float* l_c   = wsp; wsp += (size_t)NL * 128;
    float* c_c   = wsp; wsp += (size_t)NC * 128;
    float* l_msg = wsp; wsp += (size_t)NL * 128;
    float* c_hQ  = wsp; wsp += (size_t)NC * 128;   // clause-h pong / doubles as c_msg buffer
    float* l2c   = wsp; wsp += (size_t)NC * 128;
    float* c2l = l_msg;  // gather #2 writes here after gather #1 consumed l_msg

    unsigned short* us = (unsigned short*)wsp;
    unsigned short* mlpLh = us; us += 3 * 128 * 128;
    unsigned short* mlpLl = us; us += 3 * 128 * 128;
    unsigned short* mlpCh = us; us += 3 * 128 * 128;
    unsigned short* mlpCl = us; us += 3 * 128 * 128;
    unsigned short* lstmLh = us; us += 512 * 384;
    unsigned short* lstmLl = us; us += 512 * 384;
    unsigned short* lstmCh = us; us += 512 * 256;
    unsigned short* lstmCl = us; us += 512 * 256;

    int* ip = (int*)us;
    int* cnt_c    = ip; ip += NC;
    int* rowptr_c = ip; ip += NC + 1;
    int* cur_c    = ip; ip += NC;
    int* eidx_c   = ip; ip += 2 * NE;
    int* cnt_l    = ip; ip += NL;
    int* rowptr_l = ip; ip += NL + 1;
    int* cur_l    = ip; ip += NL;
    int* eidx_l   = ip; ip += 2 * NE;
    int* part_c   = ip; ip += 256;
    int* part_l   = ip; ip += 256;

    // init states
    hipMemcpyAsync(l_hA, l_pos, (size_t)NV * 128 * 4, hipMemcpyDeviceToDevice, stream);
    hipMemcpyAsync(l_hA + (size_t)NV * 128, l_neg, (size_t)NV * 128 * 4, hipMemcpyDeviceToDevice, stream);
    hipMemcpyAsync(c_hP, c_emb, (size_t)NC * 128 * 4, hipMemcpyDeviceToDevice, stream);
    hipMemsetAsync(l_c, 0, (size_t)NL * 128 * 4, stream);
    hipMemsetAsync(c_c, 0, (size_t)NC * 128 * 4, stream);

    // pack weights (once per call)
    pack_mlp_frag<<<24, 256, 0, stream>>>(l_mlp_W, mlpLh, mlpLl);
    pack_mlp_frag<<<24, 256, 0, stream>>>(c_mlp_W, mlpCh, mlpCl);
    pack_lstm_frag<<<96, 256, 0, stream>>>(l_Wih, l_Whh, 256, 12, lstmLh, lstmLl);
    pack_lstm_frag<<<64, 256, 0, stream>>>(c_Wih, c_Whh, 128, 8, lstmCh, lstmCl);

    // ---- CSR build (once per call; graph static across rounds) ----
    hipMemsetAsync(cnt_c, 0, NC * sizeof(int), stream);
    hipMemsetAsync(cnt_l, 0, NL * sizeof(int), stream);
    constexpr int EB = (NE + 255) / 256;
    csr_hist_k<<<EB, 256, 0, stream>>>(pos_src, pos_dst, neg_src, neg_dst, cnt_c, cnt_l);
    constexpr int NBC = (NC + 1023) / 1024;
    constexpr int NBL = (NL + 1023) / 1024;
    scan_p1<<<NBC, 256, 0, stream>>>(cnt_c, part_c, NC);
    scan_p2<<<1, 256, 0, stream>>>(part_c, NBC, rowptr_c + NC);
    scan_p3<<<NBC, 256, 0, stream>>>(cnt_c, part_c, rowptr_c, cur_c, NC);
    scan_p1<<<NBL, 256, 0, stream>>>(cnt_l, part_l, NL);
    scan_p2<<<1, 256, 0, stream>>>(part_l, NBL, rowptr_l + NL);
    scan_p3<<<NBL, 256, 0, stream>>>(cnt_l, part_l, rowptr_l, cur_l, NL);
    csr_fill_k<<<EB, 256, 0, stream>>>(pos_src, pos_dst, neg_src, neg_dst,
                                       cur_c, eidx_c, cur_l, eidx_l);

    float* l_cur = l_hA;
    float* l_nxt = l_hB;
    float* c_cur = c_hP;
    float* c_oth = c_hQ;

    for (int r = 0; r < NROUNDS; r++) {
        // MLPs: l_cur -> l_msg ; c_cur -> c_oth (c_msg lives in the dead clause-h buffer)
        mlp3_v3<<<(NL + 127) / 128, 256, 0, stream>>>(l_cur, mlpLh, mlpLl, l_mlp_b, l_msg, NL);
        mlp3_v3<<<(NC + 127) / 128, 256, 0, stream>>>(c_cur, mlpCh, mlpCl, c_mlp_b, c_oth, NC);

        // gathers: l2c from l_msg ; c2l (aliases l_msg) from c_oth
        gather_sum_k<<<NC * 64 / 256, 256, 0, stream>>>(l_msg, rowptr_c, eidx_c, l2c, NC);
        gather_sum_k<<<NL * 64 / 256, 256, 0, stream>>>(c_oth, rowptr_l, eidx_l, c2l, NL);

        // literal LSTM: x = [c2l | flip(l_cur) | l_cur] -> l_nxt (l_c in place)
        lstm_v3<12, true><<<dim3(4, 256), 256, 0, stream>>>(
            c2l, l_cur, l_cur, lstmLh, lstmLl, l_bih, l_bhh, l_c, l_nxt, NL);
        // clause LSTM: x = [l2c | c_cur] -> h into c_oth (c_msg already consumed; c_c in place)
        lstm_v3<8, false><<<dim3(4, 256), 256, 0, stream>>>(
            l2c, c_cur, nullptr, lstmCh, lstmCl, c_bih, c_bhh, c_c, c_oth, NC);

        float* t2 = l_cur; l_cur = l_nxt; l_nxt = t2;
        t2 = c_cur; c_cur = c_oth; c_oth = t2;
    }
    // 26 even rounds: l_cur == l_hA (d_out), c_cur == c_hP (d_out).
    (void)in_sizes; (void)n_in; (void)out_size; (void)ws_size;
}

// Round 9
// 27847.040 us; speedup vs baseline: 1.5119x; 1.5119x over previous
//
#include <hip/hip_runtime.h>
#include <math.h>

typedef __attribute__((ext_vector_type(8))) short short8;
typedef __attribute__((ext_vector_type(4))) float f32x4;

constexpr int NV = 50000;    // V
constexpr int NL = 100000;   // 2V literal rows
constexpr int NC = 200000;   // clauses
constexpr int NE = 300000;   // edges per polarity
constexpr int NROUNDS = 26;

// NOTE (r8 post-mortem): epilogue math must be relative-error-only. tanh via
// 1 - 2/(e^2x+1) has additive ~ulp(1)=6e-8 cancellation error at small x; with
// O(1e-6) recurrent states over 26 rounds that alone breaks the 8.8e-8 threshold.
__device__ __forceinline__ float sigf(float x) { return 1.0f / (1.0f + __expf(-x)); }

// in-register f32 -> bf16 hi/lo split (truncation; combined rel err ~2^-16)
__device__ __forceinline__ void split8(const float* a, short8& h, short8& l) {
#pragma unroll
    for (int j = 0; j < 8; j++) {
        unsigned u = __float_as_uint(a[j]);
        h[j] = (short)(u >> 16);
        float lf = a[j] - __uint_as_float(u & 0xffff0000u);
        l[j] = (short)(__float_as_uint(lf) >> 16);
    }
}
__device__ __forceinline__ void split1(float x, unsigned short* h, unsigned short* l) {
    unsigned u = __float_as_uint(x);
    *h = (unsigned short)(u >> 16);
    float lf = x - __uint_as_float(u & 0xffff0000u);
    *l = (unsigned short)(__float_as_uint(lf) >> 16);
}

// weight split with RTN on both halves (one-time prep)
__device__ __forceinline__ void splitw(float x, unsigned short* h, unsigned short* l) {
    unsigned u = __float_as_uint(x);
    unsigned hr = (u + 0x7fffu + ((u >> 16) & 1u)) & 0xffff0000u;
    float lf = x - __uint_as_float(hr);
    unsigned ul = __float_as_uint(lf);
    *h = (unsigned short)(hr >> 16);
    *l = (unsigned short)((ul + 0x7fffu + ((ul >> 16) & 1u)) >> 16);
}

// ======== weight prep: fragment-major packed layouts ========
// frag id: (((kt*NT + tile)*64 + lane)*8 + j); elem = W^T[n = tile*16 + (lane&15)][k = kt*32 + (lane>>4)*8 + j]

__global__ __launch_bounds__(256) void pack_mlp_frag(
    const float* __restrict__ W, unsigned short* __restrict__ Wh, unsigned short* __restrict__ Wl)
{
    int fid = blockIdx.x * 256 + threadIdx.x;   // 3*4*8*64 = 6144
    if (fid >= 6144) return;
    int lane = fid & 63;
    int tile = (fid >> 6) & 7;
    int kt = (fid >> 9) & 3;
    int layer = fid >> 11;
    int l15 = lane & 15, lg = lane >> 4;
    int n = tile * 16 + l15;
#pragma unroll
    for (int j = 0; j < 8; j++) {
        int k = kt * 32 + lg * 8 + j;
        unsigned short h, l;
        splitw(W[layer * 16384 + k * 128 + n], &h, &l);
        Wh[(size_t)fid * 8 + j] = h;
        Wl[(size_t)fid * 8 + j] = l;
    }
}

__global__ __launch_bounds__(256) void pack_lstm_frag(
    const float* __restrict__ Wih, const float* __restrict__ Whh, int kih, int nstep,
    unsigned short* __restrict__ Wh, unsigned short* __restrict__ Wl)
{
    int fid = blockIdx.x * 256 + threadIdx.x;   // nstep*32*64
    if (fid >= nstep * 2048) return;
    int lane = fid & 63;
    int tile = (fid >> 6) & 31;
    int kt = fid >> 11;
    int l15 = lane & 15, lg = lane >> 4;
    int n = tile * 16 + l15;
#pragma unroll
    for (int j = 0; j < 8; j++) {
        int k = kt * 32 + lg * 8 + j;
        float v = (k < kih) ? Wih[n * kih + k] : Whh[(n << 7) + (k - kih)];
        unsigned short h, l;
        splitw(v, &h, &l);
        Wh[(size_t)fid * 8 + j] = h;
        Wl[(size_t)fid * 8 + j] = l;
    }
}

// ================= CSR build (once per call) =================
__global__ __launch_bounds__(256) void csr_hist_k(
    const int* __restrict__ ps, const int* __restrict__ pd,
    const int* __restrict__ ns, const int* __restrict__ nd,
    int* __restrict__ cnt_c, int* __restrict__ cnt_l)
{
    int e = blockIdx.x * 256 + threadIdx.x;
    if (e >= NE) return;
    atomicAdd(&cnt_c[pd[e]], 1);
    atomicAdd(&cnt_c[nd[e]], 1);
    atomicAdd(&cnt_l[ps[e]], 1);
    atomicAdd(&cnt_l[NV + ns[e]], 1);
}

__global__ __launch_bounds__(256) void scan_p1(
    const int* __restrict__ cnt, int* __restrict__ partials, int n)
{
    __shared__ int sdata[256];
    int t = threadIdx.x, b = blockIdx.x;
    int base = b * 1024 + t * 4;
    int s = 0;
#pragma unroll
    for (int j = 0; j < 4; j++) { int i = base + j; if (i < n) s += cnt[i]; }
    sdata[t] = s; __syncthreads();
    for (int st = 128; st > 0; st >>= 1) {
        if (t < st) sdata[t] += sdata[t + st];
        __syncthreads();
    }
    if (t == 0) partials[b] = sdata[0];
}

__global__ __launch_bounds__(256) void scan_p2(int* __restrict__ partials, int nb, int* __restrict__ rowptr_end)
{
    __shared__ int sdata[256];
    int t = threadIdx.x;
    int v = (t < nb) ? partials[t] : 0;
    int x = v;
    sdata[t] = x; __syncthreads();
    for (int st = 1; st < 256; st <<= 1) {
        int y = (t >= st) ? sdata[t - st] : 0;
        __syncthreads();
        x += y; sdata[t] = x;
        __syncthreads();
    }
    if (t < nb) partials[t] = x - v;
    if (t == 255) *rowptr_end = sdata[255];
}

__global__ __launch_bounds__(256) void scan_p3(
    const int* __restrict__ cnt, const int* __restrict__ partials,
    int* __restrict__ rowptr, int* __restrict__ cursor, int n)
{
    __shared__ int sdata[256];
    int t = threadIdx.x, b = blockIdx.x;
    int base = b * 1024 + t * 4;
    int v[4]; int s = 0;
#pragma unroll
    for (int j = 0; j < 4; j++) { int i = base + j; v[j] = (i < n) ? cnt[i] : 0; s += v[j]; }
    int x = s;
    sdata[t] = x; __syncthreads();
    for (int st = 1; st < 256; st <<= 1) {
        int y = (t >= st) ? sdata[t - st] : 0;
        __syncthreads();
        x += y; sdata[t] = x;
        __syncthreads();
    }
    int off = partials[b] + x - s;
#pragma unroll
    for (int j = 0; j < 4; j++) {
        int i = base + j;
        if (i < n) { rowptr[i] = off; cursor[i] = off; off += v[j]; }
    }
}

__global__ __launch_bounds__(256) void csr_fill_k(
    const int* __restrict__ ps, const int* __restrict__ pd,
    const int* __restrict__ ns, const int* __restrict__ nd,
    int* __restrict__ cur_c, int* __restrict__ eidx_c,
    int* __restrict__ cur_l, int* __restrict__ eidx_l)
{
    int e = blockIdx.x * 256 + threadIdx.x;
    if (e >= NE) return;
    int p;
    p = atomicAdd(&cur_c[pd[e]], 1); eidx_c[p] = ps[e];
    p = atomicAdd(&cur_c[nd[e]], 1); eidx_c[p] = NV + ns[e];
    p = atomicAdd(&cur_l[ps[e]], 1); eidx_l[p] = pd[e];
    p = atomicAdd(&cur_l[NV + ns[e]], 1); eidx_l[p] = nd[e];
}

// ---- gather-sum: out[row] = sum msg[eidx[j]] ; one wave per row ----
__global__ __launch_bounds__(256) void gather_sum_k(
    const float* __restrict__ msg, const int* __restrict__ rowptr,
    const int* __restrict__ eidx, float* __restrict__ out, int nrows)
{
    int row = (blockIdx.x * 256 + threadIdx.x) >> 6;
    if (row >= nrows) return;
    int lane = threadIdx.x & 63;
    int beg = rowptr[row], end = rowptr[row + 1];
    float ax = 0.f, ay = 0.f;
    for (int j = beg; j < end; j++) {
        int src = eidx[j];
        float2 v = *reinterpret_cast<const float2*>(msg + (size_t)src * 128 + lane * 2);
        ax += v.x; ay += v.y;
    }
    *reinterpret_cast<float2*>(out + (size_t)row * 128 + lane * 2) = make_float2(ax, ay);
}

// ---------------- fused 3-layer MLP v4: bf16-split LDS activations, batched B prefetch ----------------
// block 256 (4 waves), BM=64; wave tile 32 rows x 64 cols
__global__ __launch_bounds__(256, 3) void mlp3_v4(
    const float* __restrict__ x, const unsigned short* __restrict__ Wh,
    const unsigned short* __restrict__ Wl, const float* __restrict__ bias,
    float* __restrict__ y, int M)
{
    __shared__ unsigned short Xh[64][136];
    __shared__ unsigned short Xl[64][136];
    const int t = threadIdx.x;
    const int rb = blockIdx.x * 64;
    const int lane = t & 63, w = t >> 6, wr = w >> 1, wc = w & 1;
    const int l15 = lane & 15, lg = lane >> 4;

    // stage + split input once
#pragma unroll
    for (int j = 0; j < 8; j++) {
        int i = t + 256 * j;
        int r = i >> 5, c4 = i & 31;
        int gr = rb + r; if (gr >= M) gr = M - 1;
        float4 v = *reinterpret_cast<const float4*>(x + (size_t)gr * 128 + c4 * 4);
        const float* vp = &v.x;
#pragma unroll
        for (int e = 0; e < 4; e++) {
            unsigned short h, l;
            split1(vp[e], &h, &l);
            Xh[r][c4 * 4 + e] = h;
            Xl[r][c4 * 4 + e] = l;
        }
    }
    __syncthreads();

    for (int layer = 0; layer < 3; layer++) {
        f32x4 acc[2][4];
#pragma unroll
        for (int m = 0; m < 2; m++)
#pragma unroll
            for (int nf = 0; nf < 4; nf++) acc[m][nf] = f32x4{0.f, 0.f, 0.f, 0.f};

        short8 bh[4], bl[4], bhn[4], bln[4];
#pragma unroll
        for (int nf = 0; nf < 4; nf++) {
            int tile = wc * 4 + nf;
            size_t off = ((size_t)((layer * 4 + 0) * 8 + tile) * 64 + lane) * 8;
            bh[nf] = *reinterpret_cast<const short8*>(Wh + off);
            bl[nf] = *reinterpret_cast<const short8*>(Wl + off);
        }

#pragma unroll
        for (int kt = 0; kt < 4; kt++) {
            short8 ah[2], al[2];
#pragma unroll
            for (int m = 0; m < 2; m++) {
                int row = wr * 32 + m * 16 + l15;
                ah[m] = *reinterpret_cast<const short8*>(&Xh[row][kt * 32 + lg * 8]);
                al[m] = *reinterpret_cast<const short8*>(&Xl[row][kt * 32 + lg * 8]);
            }
            if (kt < 3) {
#pragma unroll
                for (int nf = 0; nf < 4; nf++) {
                    int tile = wc * 4 + nf;
                    size_t off = ((size_t)((layer * 4 + kt + 1) * 8 + tile) * 64 + lane) * 8;
                    bhn[nf] = *reinterpret_cast<const short8*>(Wh + off);
                    bln[nf] = *reinterpret_cast<const short8*>(Wl + off);
                }
            }
#pragma unroll
            for (int nf = 0; nf < 4; nf++)
#pragma unroll
                for (int m = 0; m < 2; m++)
                    acc[m][nf] = __builtin_amdgcn_mfma_f32_16x16x32_bf16(ah[m], bh[nf], acc[m][nf], 0, 0, 0);
#pragma unroll
            for (int nf = 0; nf < 4; nf++)
#pragma unroll
                for (int m = 0; m < 2; m++)
                    acc[m][nf] = __builtin_amdgcn_mfma_f32_16x16x32_bf16(ah[m], bl[nf], acc[m][nf], 0, 0, 0);
#pragma unroll
            for (int nf = 0; nf < 4; nf++)
#pragma unroll
                for (int m = 0; m < 2; m++)
                    acc[m][nf] = __builtin_amdgcn_mfma_f32_16x16x32_bf16(al[m], bh[nf], acc[m][nf], 0, 0, 0);
            if (kt < 3) {
#pragma unroll
                for (int nf = 0; nf < 4; nf++) { bh[nf] = bhn[nf]; bl[nf] = bln[nf]; }
            }
        }

        float bv[4];
#pragma unroll
        for (int nf = 0; nf < 4; nf++) bv[nf] = bias[layer * 128 + wc * 64 + nf * 16 + l15];
        __syncthreads();   // all Xh/Xl reads done
        if (layer < 2) {
#pragma unroll
            for (int m = 0; m < 2; m++)
#pragma unroll
                for (int nf = 0; nf < 4; nf++)
#pragma unroll
                    for (int rr = 0; rr < 4; rr++) {
                        float v = fmaxf(acc[m][nf][rr] + bv[nf], 0.f);
                        unsigned short h, l;
                        split1(v, &h, &l);
                        int rw = wr * 32 + m * 16 + lg * 4 + rr;
                        int cl = wc * 64 + nf * 16 + l15;
                        Xh[rw][cl] = h;
                        Xl[rw][cl] = l;
                    }
            __syncthreads();
        } else {
#pragma unroll
            for (int m = 0; m < 2; m++)
#pragma unroll
                for (int rr = 0; rr < 4; rr++) {
                    int gr = rb + wr * 32 + m * 16 + lg * 4 + rr;
                    if (gr < M) {
#pragma unroll
                        for (int nf = 0; nf < 4; nf++)
                            y[(size_t)gr * 128 + wc * 64 + nf * 16 + l15] = acc[m][nf][rr] + bv[nf];
                    }
                }
        }
    }
}

// ---------------- LSTM v4: no LDS/barriers; batched B loads, software-pipelined ----------------
// block 512 thr (8 waves): wr = w>>2 (rows), wc = w&3 (col quarter).
// Wave tile: 32 rows (m 0..1) x 128 gate-cols (4 gates x 2 subtiles).
template <int NKT, bool FLIP>
__global__ __launch_bounds__(512, 2) void lstm_v4(
    const float* __restrict__ A0, const float* __restrict__ A1, const float* __restrict__ A2,
    const unsigned short* __restrict__ Bh_g, const unsigned short* __restrict__ Bl_g,
    const float* __restrict__ bih, const float* __restrict__ bhh,
    float* __restrict__ c_st, float* __restrict__ h_out, int M)
{
    const int t = threadIdx.x;
    const int rb = blockIdx.x * 64;
    const int lane = t & 63, w = t >> 6, wr = w >> 2, wc = w & 3;
    const int l15 = lane & 15, lg = lane >> 4;

    int r0[2], rF[2];
#pragma unroll
    for (int m = 0; m < 2; m++) {
        int r = rb + wr * 32 + m * 16 + l15;
        if (r >= M) r = M - 1;
        r0[m] = r;
        rF[m] = FLIP ? ((r < NV) ? r + NV : r - NV) : r;
    }

    f32x4 acc[2][8];   // [m][g*2+u]
#pragma unroll
    for (int m = 0; m < 2; m++)
#pragma unroll
        for (int i = 0; i < 8; i++) acc[m][i] = f32x4{0.f, 0.f, 0.f, 0.f};

    short8 bh[8], bl[8], bhn[8];
    float4 avc[2][2], avn[2][2];

    // prologue: B-hi frags for kt=0, A for kt=0
#pragma unroll
    for (int i = 0; i < 8; i++) {
        int tile = (i >> 1) * 8 + wc * 2 + (i & 1);
        size_t off = ((size_t)tile * 64 + lane) * 8;
        bh[i] = *reinterpret_cast<const short8*>(Bh_g + off);
    }
#pragma unroll
    for (int m = 0; m < 2; m++) {
        const float* p = A0 + (size_t)r0[m] * 128 + lg * 8;
        avc[m][0] = *reinterpret_cast<const float4*>(p);
        avc[m][1] = *reinterpret_cast<const float4*>(p + 4);
    }

#pragma unroll
    for (int kt = 0; kt < NKT; kt++) {
        // batch-issue B-lo frags for this kt
#pragma unroll
        for (int i = 0; i < 8; i++) {
            int tile = (i >> 1) * 8 + wc * 2 + (i & 1);
            size_t off = ((size_t)(kt * 32 + tile) * 64 + lane) * 8;
            bl[i] = *reinterpret_cast<const short8*>(Bl_g + off);
        }
        // split current A
        short8 ah[2], al[2];
#pragma unroll
        for (int m = 0; m < 2; m++) {
            float av[8];
            *reinterpret_cast<float4*>(&av[0]) = avc[m][0];
            *reinterpret_cast<float4*>(&av[4]) = avc[m][1];
            split8(av, ah[m], al[m]);
        }
        // phase 1: ah x bh  (covers bl load latency)
#pragma unroll
        for (int i = 0; i < 8; i++)
#pragma unroll
            for (int m = 0; m < 2; m++)
                acc[m][i] = __builtin_amdgcn_mfma_f32_16x16x32_bf16(ah[m], bh[i], acc[m][i], 0, 0, 0);
        // batch-issue next-kt B-hi frags + next-kt A
        if (kt + 1 < NKT) {
#pragma unroll
            for (int i = 0; i < 8; i++) {
                int tile = (i >> 1) * 8 + wc * 2 + (i & 1);
                size_t off = ((size_t)((kt + 1) * 32 + tile) * 64 + lane) * 8;
                bhn[i] = *reinterpret_cast<const short8*>(Bh_g + off);
            }
            const int seg = (kt + 1) >> 2;
            const float* src = (seg == 0) ? A0 : ((seg == 1) ? A1 : A2);
            const bool useF = FLIP && (seg == 1);
            const int kc = ((kt + 1) & 3) * 32 + lg * 8;
#pragma unroll
            for (int m = 0; m < 2; m++) {
                const float* p = src + (size_t)(useF ? rF[m] : r0[m]) * 128 + kc;
                avn[m][0] = *reinterpret_cast<const float4*>(p);
                avn[m][1] = *reinterpret_cast<const float4*>(p + 4);
            }
        }
        // phase 2: ah x bl
#pragma unroll
        for (int i = 0; i < 8; i++)
#pragma unroll
            for (int m = 0; m < 2; m++)
                acc[m][i] = __builtin_amdgcn_mfma_f32_16x16x32_bf16(ah[m], bl[i], acc[m][i], 0, 0, 0);
        // phase 3: al x bh
#pragma unroll
        for (int i = 0; i < 8; i++)
#pragma unroll
            for (int m = 0; m < 2; m++)
                acc[m][i] = __builtin_amdgcn_mfma_f32_16x16x32_bf16(al[m], bh[i], acc[m][i], 0, 0, 0);
        // rotate pipeline regs
        if (kt + 1 < NKT) {
#pragma unroll
            for (int i = 0; i < 8; i++) bh[i] = bhn[i];
#pragma unroll
            for (int m = 0; m < 2; m++) { avc[m][0] = avn[m][0]; avc[m][1] = avn[m][1]; }
        }
    }

    // epilogue: bias + activations + state update (precise transcendentals — see note)
    float bs4[4][2];
#pragma unroll
    for (int g = 0; g < 4; g++)
#pragma unroll
        for (int u = 0; u < 2; u++) {
            int colc = wc * 32 + u * 16 + l15;
            bs4[g][u] = bih[g * 128 + colc] + bhh[g * 128 + colc];
        }
#pragma unroll
    for (int m = 0; m < 2; m++)
#pragma unroll
        for (int rr = 0; rr < 4; rr++) {
            int gr = rb + wr * 32 + m * 16 + lg * 4 + rr;
            if (gr >= M) continue;
#pragma unroll
            for (int u = 0; u < 2; u++) {
                int colc = wc * 32 + u * 16 + l15;
                float gi = acc[m][0 + u][rr] + bs4[0][u];
                float gf = acc[m][2 + u][rr] + bs4[1][u];
                float gg = acc[m][4 + u][rr] + bs4[2][u];
                float go = acc[m][6 + u][rr] + bs4[3][u];
                size_t p = (size_t)gr * 128 + colc;
                float cold = c_st[p];
                float cn = sigf(gf) * cold + sigf(gi) * tanhf(gg);
                float hn = sigf(go) * tanhf(cn);
                c_st[p] = cn;
                h_out[p] = hn;
            }
        }
}

extern "C" void kernel_launch(void* const* d_in, const int* in_sizes, int n_in,
                              void* d_out, int out_size, void* d_ws, size_t ws_size,
                              hipStream_t stream)
{
    const float* l_pos   = (const float*)d_in[0];
    const float* l_neg   = (const float*)d_in[1];
    const float* c_emb   = (const float*)d_in[2];
    const float* l_mlp_W = (const float*)d_in[3];
    const float* l_mlp_b = (const float*)d_in[4];
    const float* c_mlp_W = (const float*)d_in[5];
    const float* c_mlp_b = (const float*)d_in[6];
    const float* l_Wih   = (const float*)d_in[7];
    const float* l_Whh   = (const float*)d_in[8];
    const float* l_bih   = (const float*)d_in[9];
    const float* l_bhh   = (const float*)d_in[10];
    const float* c_Wih   = (const float*)d_in[11];
    const float* c_Whh   = (const float*)d_in[12];
    const float* c_bih   = (const float*)d_in[13];
    const float* c_bhh   = (const float*)d_in[14];
    const int* pos_src   = (const int*)d_in[15];
    const int* pos_dst   = (const int*)d_in[16];
    const int* neg_src   = (const int*)d_in[17];
    const int* neg_dst   = (const int*)d_in[18];

    float* out  = (float*)d_out;
    float* l_hA = out;
    float* c_hP = out + (size_t)NL * 128;     // clause-h ping (final resting place)

    float* wsp = (float*)d_ws;
    float* l_hB  = wsp; wsp += (size_t)NL * 128;
    float* l_c   = wsp; wsp += (size_t)NL * 128;
    float* c_c   = wsp; wsp += (size_t)NC * 128;
    float* l_msg = wsp; wsp += (size_t)NL * 128;
    float* c_hQ  = wsp; wsp += (size_t)NC * 128;   // clause-h pong / doubles as c_msg buffer
    float* l2c   = wsp; wsp += (size_t)NC * 128;
    float* c2l = l_msg;  // gather #2 writes here after gather #1 consumed l_msg

    unsigned short* us = (unsigned short*)wsp;
    unsigned short* mlpLh = us; us += 3 * 128 * 128;
    unsigned short* mlpLl = us; us += 3 * 128 * 128;
    unsigned short* mlpCh = us; us += 3 * 128 * 128;
    unsigned short* mlpCl = us; us += 3 * 128 * 128;
    unsigned short* lstmLh = us; us += 512 * 384;
    unsigned short* lstmLl = us; us += 512 * 384;
    unsigned short* lstmCh = us; us += 512 * 256;
    unsigned short* lstmCl = us; us += 512 * 256;

    int* ip = (int*)us;
    int* cnt_c    = ip; ip += NC;
    int* rowptr_c = ip; ip += NC + 1;
    int* cur_c    = ip; ip += NC;
    int* eidx_c   = ip; ip += 2 * NE;
    int* cnt_l    = ip; ip += NL;
    int* rowptr_l = ip; ip += NL + 1;
    int* cur_l    = ip; ip += NL;
    int* eidx_l   = ip; ip += 2 * NE;
    int* part_c   = ip; ip += 256;
    int* part_l   = ip; ip += 256;

    // init states
    hipMemcpyAsync(l_hA, l_pos, (size_t)NV * 128 * 4, hipMemcpyDeviceToDevice, stream);
    hipMemcpyAsync(l_hA + (size_t)NV * 128, l_neg, (size_t)NV * 128 * 4, hipMemcpyDeviceToDevice, stream);
    hipMemcpyAsync(c_hP, c_emb, (size_t)NC * 128 * 4, hipMemcpyDeviceToDevice, stream);
    hipMemsetAsync(l_c, 0, (size_t)NL * 128 * 4, stream);
    hipMemsetAsync(c_c, 0, (size_t)NC * 128 * 4, stream);

    // pack weights (once per call)
    pack_mlp_frag<<<24, 256, 0, stream>>>(l_mlp_W, mlpLh, mlpLl);
    pack_mlp_frag<<<24, 256, 0, stream>>>(c_mlp_W, mlpCh, mlpCl);
    pack_lstm_frag<<<96, 256, 0, stream>>>(l_Wih, l_Whh, 256, 12, lstmLh, lstmLl);
    pack_lstm_frag<<<64, 256, 0, stream>>>(c_Wih, c_Whh, 128, 8, lstmCh, lstmCl);

    // ---- CSR build (once per call; graph static across rounds) ----
    hipMemsetAsync(cnt_c, 0, NC * sizeof(int), stream);
    hipMemsetAsync(cnt_l, 0, NL * sizeof(int), stream);
    constexpr int EB = (NE + 255) / 256;
    csr_hist_k<<<EB, 256, 0, stream>>>(pos_src, pos_dst, neg_src, neg_dst, cnt_c, cnt_l);
    constexpr int NBC = (NC + 1023) / 1024;
    constexpr int NBL = (NL + 1023) / 1024;
    scan_p1<<<NBC, 256, 0, stream>>>(cnt_c, part_c, NC);
    scan_p2<<<1, 256, 0, stream>>>(part_c, NBC, rowptr_c + NC);
    scan_p3<<<NBC, 256, 0, stream>>>(cnt_c, part_c, rowptr_c, cur_c, NC);
    scan_p1<<<NBL, 256, 0, stream>>>(cnt_l, part_l, NL);
    scan_p2<<<1, 256, 0, stream>>>(part_l, NBL, rowptr_l + NL);
    scan_p3<<<NBL, 256, 0, stream>>>(cnt_l, part_l, rowptr_l, cur_l, NL);
    csr_fill_k<<<EB, 256, 0, stream>>>(pos_src, pos_dst, neg_src, neg_dst,
                                       cur_c, eidx_c, cur_l, eidx_l);

    float* l_cur = l_hA;
    float* l_nxt = l_hB;
    float* c_cur = c_hP;
    float* c_oth = c_hQ;

    for (int r = 0; r < NROUNDS; r++) {
        // MLPs: l_cur -> l_msg ; c_cur -> c_oth (c_msg lives in the dead clause-h buffer)
        mlp3_v4<<<(NL + 63) / 64, 256, 0, stream>>>(l_cur, mlpLh, mlpLl, l_mlp_b, l_msg, NL);
        mlp3_v4<<<(NC + 63) / 64, 256, 0, stream>>>(c_cur, mlpCh, mlpCl, c_mlp_b, c_oth, NC);

        // gathers: l2c from l_msg ; c2l (aliases l_msg) from c_oth
        gather_sum_k<<<NC * 64 / 256, 256, 0, stream>>>(l_msg, rowptr_c, eidx_c, l2c, NC);
        gather_sum_k<<<NL * 64 / 256, 256, 0, stream>>>(c_oth, rowptr_l, eidx_l, c2l, NL);

        // literal LSTM: x = [c2l | flip(l_cur) | l_cur] -> l_nxt (l_c in place)
        lstm_v4<12, true><<<(NL + 63) / 64, 512, 0, stream>>>(
            c2l, l_cur, l_cur, lstmLh, lstmLl, l_bih, l_bhh, l_c, l_nxt, NL);
        // clause LSTM: x = [l2c | c_cur] -> h into c_oth (c_msg already consumed; c_c in place)
        lstm_v4<8, false><<<(NC + 63) / 64, 512, 0, stream>>>(
            l2c, c_cur, nullptr, lstmCh, lstmCl, c_bih, c_bhh, c_c, c_oth, NC);

        float* t2 = l_cur; l_cur = l_nxt; l_nxt = t2;
        t2 = c_cur; c_cur = c_oth; c_oth = t2;
    }
    // 26 even rounds: l_cur == l_hA (d_out), c_cur == c_hP (d_out).
    (void)in_sizes; (void)n_in; (void)out_size; (void)ws_size;
}

// Round 10
// 22516.147 us; speedup vs baseline: 1.8699x; 1.2368x over previous
//
#include <hip/hip_runtime.h>
#include <math.h>

typedef __attribute__((ext_vector_type(8))) short short8;
typedef __attribute__((ext_vector_type(4))) float f32x4;

constexpr int NV = 50000;    // V
constexpr int NL = 100000;   // 2V literal rows
constexpr int NC = 200000;   // clauses
constexpr int NE = 300000;   // edges per polarity
constexpr int NROUNDS = 26;

// NOTE (r8 post-mortem): epilogue math must be relative-error-only. tanh via
// 1 - 2/(e^2x+1) has additive ~ulp(1)=6e-8 cancellation error at small x; with
// O(1e-6) recurrent states over 26 rounds that alone breaks the 8.8e-8 threshold.
__device__ __forceinline__ float sigf(float x) { return 1.0f / (1.0f + __expf(-x)); }

// in-register f32 -> bf16 hi/lo split (truncation; combined rel err ~2^-16)
__device__ __forceinline__ void split8(const float* a, short8& h, short8& l) {
#pragma unroll
    for (int j = 0; j < 8; j++) {
        unsigned u = __float_as_uint(a[j]);
        h[j] = (short)(u >> 16);
        float lf = a[j] - __uint_as_float(u & 0xffff0000u);
        l[j] = (short)(__float_as_uint(lf) >> 16);
    }
}
__device__ __forceinline__ void split1(float x, unsigned short* h, unsigned short* l) {
    unsigned u = __float_as_uint(x);
    *h = (unsigned short)(u >> 16);
    float lf = x - __uint_as_float(u & 0xffff0000u);
    *l = (unsigned short)(__float_as_uint(lf) >> 16);
}

// weight split with RTN on both halves (one-time prep)
__device__ __forceinline__ void splitw(float x, unsigned short* h, unsigned short* l) {
    unsigned u = __float_as_uint(x);
    unsigned hr = (u + 0x7fffu + ((u >> 16) & 1u)) & 0xffff0000u;
    float lf = x - __uint_as_float(hr);
    unsigned ul = __float_as_uint(lf);
    *h = (unsigned short)(hr >> 16);
    *l = (unsigned short)((ul + 0x7fffu + ((ul >> 16) & 1u)) >> 16);
}

// ======== weight prep: fragment-major packed layouts ========
// frag id: (((kt*NT + tile)*64 + lane)*8 + j); elem = W^T[n = tile*16 + (lane&15)][k = kt*32 + (lane>>4)*8 + j]

__global__ __launch_bounds__(256) void pack_mlp_frag(
    const float* __restrict__ W, unsigned short* __restrict__ Wh, unsigned short* __restrict__ Wl)
{
    int fid = blockIdx.x * 256 + threadIdx.x;   // 3*4*8*64 = 6144
    if (fid >= 6144) return;
    int lane = fid & 63;
    int tile = (fid >> 6) & 7;
    int kt = (fid >> 9) & 3;
    int layer = fid >> 11;
    int l15 = lane & 15, lg = lane >> 4;
    int n = tile * 16 + l15;
#pragma unroll
    for (int j = 0; j < 8; j++) {
        int k = kt * 32 + lg * 8 + j;
        unsigned short h, l;
        splitw(W[layer * 16384 + k * 128 + n], &h, &l);
        Wh[(size_t)fid * 8 + j] = h;
        Wl[(size_t)fid * 8 + j] = l;
    }
}

__global__ __launch_bounds__(256) void pack_lstm_frag(
    const float* __restrict__ Wih, const float* __restrict__ Whh, int kih, int nstep,
    unsigned short* __restrict__ Wh, unsigned short* __restrict__ Wl)
{
    int fid = blockIdx.x * 256 + threadIdx.x;   // nstep*32*64
    if (fid >= nstep * 2048) return;
    int lane = fid & 63;
    int tile = (fid >> 6) & 31;
    int kt = fid >> 11;
    int l15 = lane & 15, lg = lane >> 4;
    int n = tile * 16 + l15;
#pragma unroll
    for (int j = 0; j < 8; j++) {
        int k = kt * 32 + lg * 8 + j;
        float v = (k < kih) ? Wih[n * kih + k] : Whh[(n << 7) + (k - kih)];
        unsigned short h, l;
        splitw(v, &h, &l);
        Wh[(size_t)fid * 8 + j] = h;
        Wl[(size_t)fid * 8 + j] = l;
    }
}

// ================= CSR build (once per call) =================
__global__ __launch_bounds__(256) void csr_hist_k(
    const int* __restrict__ ps, const int* __restrict__ pd,
    const int* __restrict__ ns, const int* __restrict__ nd,
    int* __restrict__ cnt_c, int* __restrict__ cnt_l)
{
    int e = blockIdx.x * 256 + threadIdx.x;
    if (e >= NE) return;
    atomicAdd(&cnt_c[pd[e]], 1);
    atomicAdd(&cnt_c[nd[e]], 1);
    atomicAdd(&cnt_l[ps[e]], 1);
    atomicAdd(&cnt_l[NV + ns[e]], 1);
}

__global__ __launch_bounds__(256) void scan_p1(
    const int* __restrict__ cnt, int* __restrict__ partials, int n)
{
    __shared__ int sdata[256];
    int t = threadIdx.x, b = blockIdx.x;
    int base = b * 1024 + t * 4;
    int s = 0;
#pragma unroll
    for (int j = 0; j < 4; j++) { int i = base + j; if (i < n) s += cnt[i]; }
    sdata[t] = s; __syncthreads();
    for (int st = 128; st > 0; st >>= 1) {
        if (t < st) sdata[t] += sdata[t + st];
        __syncthreads();
    }
    if (t == 0) partials[b] = sdata[0];
}

__global__ __launch_bounds__(256) void scan_p2(int* __restrict__ partials, int nb, int* __restrict__ rowptr_end)
{
    __shared__ int sdata[256];
    int t = threadIdx.x;
    int v = (t < nb) ? partials[t] : 0;
    int x = v;
    sdata[t] = x; __syncthreads();
    for (int st = 1; st < 256; st <<= 1) {
        int y = (t >= st) ? sdata[t - st] : 0;
        __syncthreads();
        x += y; sdata[t] = x;
        __syncthreads();
    }
    if (t < nb) partials[t] = x - v;
    if (t == 255) *rowptr_end = sdata[255];
}

__global__ __launch_bounds__(256) void scan_p3(
    const int* __restrict__ cnt, const int* __restrict__ partials,
    int* __restrict__ rowptr, int* __restrict__ cursor, int n)
{
    __shared__ int sdata[256];
    int t = threadIdx.x, b = blockIdx.x;
    int base = b * 1024 + t * 4;
    int v[4]; int s = 0;
#pragma unroll
    for (int j = 0; j < 4; j++) { int i = base + j; v[j] = (i < n) ? cnt[i] : 0; s += v[j]; }
    int x = s;
    sdata[t] = x; __syncthreads();
    for (int st = 1; st < 256; st <<= 1) {
        int y = (t >= st) ? sdata[t - st] : 0;
        __syncthreads();
        x += y; sdata[t] = x;
        __syncthreads();
    }
    int off = partials[b] + x - s;
#pragma unroll
    for (int j = 0; j < 4; j++) {
        int i = base + j;
        if (i < n) { rowptr[i] = off; cursor[i] = off; off += v[j]; }
    }
}

__global__ __launch_bounds__(256) void csr_fill_k(
    const int* __restrict__ ps, const int* __restrict__ pd,
    const int* __restrict__ ns, const int* __restrict__ nd,
    int* __restrict__ cur_c, int* __restrict__ eidx_c,
    int* __restrict__ cur_l, int* __restrict__ eidx_l)
{
    int e = blockIdx.x * 256 + threadIdx.x;
    if (e >= NE) return;
    int p;
    p = atomicAdd(&cur_c[pd[e]], 1); eidx_c[p] = ps[e];
    p = atomicAdd(&cur_c[nd[e]], 1); eidx_c[p] = NV + ns[e];
    p = atomicAdd(&cur_l[ps[e]], 1); eidx_l[p] = pd[e];
    p = atomicAdd(&cur_l[NV + ns[e]], 1); eidx_l[p] = nd[e];
}

// ---- gather-sum: out[row] = sum msg[eidx[j]] ; one wave per row ----
__global__ __launch_bounds__(256) void gather_sum_k(
    const float* __restrict__ msg, const int* __restrict__ rowptr,
    const int* __restrict__ eidx, float* __restrict__ out, int nrows)
{
    int row = (blockIdx.x * 256 + threadIdx.x) >> 6;
    if (row >= nrows) return;
    int lane = threadIdx.x & 63;
    int beg = rowptr[row], end = rowptr[row + 1];
    float ax = 0.f, ay = 0.f;
    for (int j = beg; j < end; j++) {
        int src = eidx[j];
        float2 v = *reinterpret_cast<const float2*>(msg + (size_t)src * 128 + lane * 2);
        ax += v.x; ay += v.y;
    }
    *reinterpret_cast<float2*>(out + (size_t)row * 128 + lane * 2) = make_float2(ax, ay);
}

// ---------------- fused 3-layer MLP v4: bf16-split LDS activations, batched B prefetch ----------------
// block 256 (4 waves), BM=64; wave tile 32 rows x 64 cols
__global__ __launch_bounds__(256, 3) void mlp3_v4(
    const float* __restrict__ x, const unsigned short* __restrict__ Wh,
    const unsigned short* __restrict__ Wl, const float* __restrict__ bias,
    float* __restrict__ y, int M)
{
    __shared__ unsigned short Xh[64][136];
    __shared__ unsigned short Xl[64][136];
    const int t = threadIdx.x;
    const int rb = blockIdx.x * 64;
    const int lane = t & 63, w = t >> 6, wr = w >> 1, wc = w & 1;
    const int l15 = lane & 15, lg = lane >> 4;

    // stage + split input once
#pragma unroll
    for (int j = 0; j < 8; j++) {
        int i = t + 256 * j;
        int r = i >> 5, c4 = i & 31;
        int gr = rb + r; if (gr >= M) gr = M - 1;
        float4 v = *reinterpret_cast<const float4*>(x + (size_t)gr * 128 + c4 * 4);
        const float* vp = &v.x;
#pragma unroll
        for (int e = 0; e < 4; e++) {
            unsigned short h, l;
            split1(vp[e], &h, &l);
            Xh[r][c4 * 4 + e] = h;
            Xl[r][c4 * 4 + e] = l;
        }
    }
    __syncthreads();

    for (int layer = 0; layer < 3; layer++) {
        f32x4 acc[2][4];
#pragma unroll
        for (int m = 0; m < 2; m++)
#pragma unroll
            for (int nf = 0; nf < 4; nf++) acc[m][nf] = f32x4{0.f, 0.f, 0.f, 0.f};

        short8 bh[4], bl[4], bhn[4], bln[4];
#pragma unroll
        for (int nf = 0; nf < 4; nf++) {
            int tile = wc * 4 + nf;
            size_t off = ((size_t)((layer * 4 + 0) * 8 + tile) * 64 + lane) * 8;
            bh[nf] = *reinterpret_cast<const short8*>(Wh + off);
            bl[nf] = *reinterpret_cast<const short8*>(Wl + off);
        }

#pragma unroll
        for (int kt = 0; kt < 4; kt++) {
            short8 ah[2], al[2];
#pragma unroll
            for (int m = 0; m < 2; m++) {
                int row = wr * 32 + m * 16 + l15;
                ah[m] = *reinterpret_cast<const short8*>(&Xh[row][kt * 32 + lg * 8]);
                al[m] = *reinterpret_cast<const short8*>(&Xl[row][kt * 32 + lg * 8]);
            }
            if (kt < 3) {
#pragma unroll
                for (int nf = 0; nf < 4; nf++) {
                    int tile = wc * 4 + nf;
                    size_t off = ((size_t)((layer * 4 + kt + 1) * 8 + tile) * 64 + lane) * 8;
                    bhn[nf] = *reinterpret_cast<const short8*>(Wh + off);
                    bln[nf] = *reinterpret_cast<const short8*>(Wl + off);
                }
            }
#pragma unroll
            for (int nf = 0; nf < 4; nf++)
#pragma unroll
                for (int m = 0; m < 2; m++)
                    acc[m][nf] = __builtin_amdgcn_mfma_f32_16x16x32_bf16(ah[m], bh[nf], acc[m][nf], 0, 0, 0);
#pragma unroll
            for (int nf = 0; nf < 4; nf++)
#pragma unroll
                for (int m = 0; m < 2; m++)
                    acc[m][nf] = __builtin_amdgcn_mfma_f32_16x16x32_bf16(ah[m], bl[nf], acc[m][nf], 0, 0, 0);
#pragma unroll
            for (int nf = 0; nf < 4; nf++)
#pragma unroll
                for (int m = 0; m < 2; m++)
                    acc[m][nf] = __builtin_amdgcn_mfma_f32_16x16x32_bf16(al[m], bh[nf], acc[m][nf], 0, 0, 0);
            if (kt < 3) {
#pragma unroll
                for (int nf = 0; nf < 4; nf++) { bh[nf] = bhn[nf]; bl[nf] = bln[nf]; }
            }
        }

        float bv[4];
#pragma unroll
        for (int nf = 0; nf < 4; nf++) bv[nf] = bias[layer * 128 + wc * 64 + nf * 16 + l15];
        __syncthreads();   // all Xh/Xl reads done
        if (layer < 2) {
#pragma unroll
            for (int m = 0; m < 2; m++)
#pragma unroll
                for (int nf = 0; nf < 4; nf++)
#pragma unroll
                    for (int rr = 0; rr < 4; rr++) {
                        float v = fmaxf(acc[m][nf][rr] + bv[nf], 0.f);
                        unsigned short h, l;
                        split1(v, &h, &l);
                        int rw = wr * 32 + m * 16 + lg * 4 + rr;
                        int cl = wc * 64 + nf * 16 + l15;
                        Xh[rw][cl] = h;
                        Xl[rw][cl] = l;
                    }
            __syncthreads();
        } else {
#pragma unroll
            for (int m = 0; m < 2; m++)
#pragma unroll
                for (int rr = 0; rr < 4; rr++) {
                    int gr = rb + wr * 32 + m * 16 + lg * 4 + rr;
                    if (gr < M) {
#pragma unroll
                        for (int nf = 0; nf < 4; nf++)
                            y[(size_t)gr * 128 + wc * 64 + nf * 16 + l15] = acc[m][nf][rr] + bv[nf];
                    }
                }
        }
    }
}

// ---------------- LSTM v5: m97-style LDS double-buffer, 1 barrier per K-step ----------------
// grid (4 N-slices, M/128); block 256 thr / 4 waves (wr = rows half, wc = 16-col half).
// Block tile: 128 rows x 128 gate-cols (4 gates x [s*32, s*32+32)).
// Wave tile: 64 rows x (4 gates x 16 cols); acc[4 m][4 g]; operand reuse 4x both sides.
// A tile [128 r][32 k] f32 staged with XOR swizzle (row-major 128B stride = bank conflict, G4).
// B slice per kt: 16 frag-tiles (8 hi + 8 lo) x 1KB, lane-linear.
// Staging: issue-early (global->reg before MFMA), write-late (ds_write after MFMA), 1 barrier.
template <int NKT, bool FLIP>
__global__ __launch_bounds__(256, 2) void lstm_v5(
    const float* __restrict__ A0, const float* __restrict__ A1, const float* __restrict__ A2,
    const unsigned short* __restrict__ Bh_g, const unsigned short* __restrict__ Bl_g,
    const float* __restrict__ bih, const float* __restrict__ bhh,
    float* __restrict__ c_st, float* __restrict__ h_out, int M)
{
    __shared__ float As[2][4096];            // 2 x 16KB, swizzled [128 r][32 k]
    __shared__ unsigned short Bsm[2][8192];  // 2 x 16KB, [16 frags][64 lanes][8]
    const int t = threadIdx.x;
    const int s = blockIdx.x;                // N slice 0..3
    const int rb = blockIdx.y * 128;
    const int lane = t & 63, w = t >> 6, wr = w >> 1, wc = w & 1;
    const int l15 = lane & 15, lg = lane >> 4;

    f32x4 acc[4][4];
#pragma unroll
    for (int m = 0; m < 4; m++)
#pragma unroll
        for (int g = 0; g < 4; g++) acc[m][g] = f32x4{0.f, 0.f, 0.f, 0.f};

    // ---- prologue: stage kt=0 into buffer 0 (seg 0 = A0, never flipped) ----
#pragma unroll
    for (int i = 0; i < 4; i++) {
        int idx = t + 256 * i;               // [0,1024)
        int r = idx >> 3, c4 = idx & 7;
        int gr = rb + r; if (gr >= M) gr = M - 1;
        float4 v = *reinterpret_cast<const float4*>(A0 + (size_t)gr * 128 + c4 * 4);
        int off = (r * 128 + c4 * 16) ^ ((r & 7) << 4);
        *reinterpret_cast<float4*>((char*)As[0] + off) = v;
    }
#pragma unroll
    for (int i = 0; i < 4; i++) {
        int idx = t + 256 * i;
        int f = idx >> 6, ln = idx & 63;
        int sel = f >> 3, ft = f & 7;
        int gt = (ft >> 1) * 8 + s * 2 + (ft & 1);
        const unsigned short* bsrc = sel ? Bl_g : Bh_g;
        uint4 v = *reinterpret_cast<const uint4*>(bsrc + ((size_t)gt * 64 + ln) * 8);
        *reinterpret_cast<uint4*>((char*)Bsm[0] + idx * 16) = v;
    }
    __syncthreads();

    int cur = 0;
#pragma unroll
    for (int kt = 0; kt < NKT; kt++) {
        // (1) issue next K-step's global loads (held in regs across the MFMA cluster)
        float4 a_stg[4]; uint4 b_stg[4];
        if (kt + 1 < NKT) {
            const int kn = kt + 1;
            const int seg = kn >> 2;
            const float* src = (seg == 0) ? A0 : ((seg == 1) ? A1 : A2);
            const bool useF = FLIP && (seg == 1);
            const int kco = (kn & 3) * 32;
#pragma unroll
            for (int i = 0; i < 4; i++) {
                int idx = t + 256 * i;
                int r = idx >> 3, c4 = idx & 7;
                int gr = rb + r; if (gr >= M) gr = M - 1;
                if (useF) gr = (gr < NV) ? gr + NV : gr - NV;
                a_stg[i] = *reinterpret_cast<const float4*>(src + (size_t)gr * 128 + kco + c4 * 4);
            }
#pragma unroll
            for (int i = 0; i < 4; i++) {
                int idx = t + 256 * i;
                int f = idx >> 6, ln = idx & 63;
                int sel = f >> 3, ft = f & 7;
                int gt = (ft >> 1) * 8 + s * 2 + (ft & 1);
                const unsigned short* bsrc = sel ? Bl_g : Bh_g;
                b_stg[i] = *reinterpret_cast<const uint4*>(bsrc + ((size_t)(kn * 32 + gt) * 64 + ln) * 8);
            }
        }

        // (2) compute current K-step from LDS
        const char* Ab = (const char*)As[cur];
        short8 ah[4], al[4];
#pragma unroll
        for (int m = 0; m < 4; m++) {
            int r = wr * 64 + m * 16 + l15;
            int base = r * 128 + lg * 32;
            int swz = (r & 7) << 4;
            float av[8];
            *reinterpret_cast<float4*>(&av[0]) =
                *reinterpret_cast<const float4*>(Ab + (base ^ swz));
            *reinterpret_cast<float4*>(&av[4]) =
                *reinterpret_cast<const float4*>(Ab + ((base + 16) ^ swz));
            split8(av, ah[m], al[m]);
        }
        const char* Bb = (const char*)Bsm[cur];
#pragma unroll
        for (int g = 0; g < 4; g++) {
            short8 bh = *reinterpret_cast<const short8*>(Bb + ((g * 2 + wc) * 64 + lane) * 16);
            short8 bl = *reinterpret_cast<const short8*>(Bb + ((8 + g * 2 + wc) * 64 + lane) * 16);
#pragma unroll
            for (int m = 0; m < 4; m++)
                acc[m][g] = __builtin_amdgcn_mfma_f32_16x16x32_bf16(ah[m], bh, acc[m][g], 0, 0, 0);
#pragma unroll
            for (int m = 0; m < 4; m++)
                acc[m][g] = __builtin_amdgcn_mfma_f32_16x16x32_bf16(ah[m], bl, acc[m][g], 0, 0, 0);
#pragma unroll
            for (int m = 0; m < 4; m++)
                acc[m][g] = __builtin_amdgcn_mfma_f32_16x16x32_bf16(al[m], bh, acc[m][g], 0, 0, 0);
        }

        // (3) write staged regs to the other buffer, then the single barrier
        if (kt + 1 < NKT) {
            int nb = cur ^ 1;
#pragma unroll
            for (int i = 0; i < 4; i++) {
                int idx = t + 256 * i;
                int r = idx >> 3, c4 = idx & 7;
                int off = (r * 128 + c4 * 16) ^ ((r & 7) << 4);
                *reinterpret_cast<float4*>((char*)As[nb] + off) = a_stg[i];
            }
#pragma unroll
            for (int i = 0; i < 4; i++) {
                int idx = t + 256 * i;
                *reinterpret_cast<uint4*>((char*)Bsm[nb] + idx * 16) = b_stg[i];
            }
        }
        __syncthreads();
        cur ^= 1;
    }

    // epilogue: bias + activations + state update (precise transcendentals — see note)
    const int colc = s * 32 + wc * 16 + l15;
    float bs4[4];
#pragma unroll
    for (int g = 0; g < 4; g++) bs4[g] = bih[g * 128 + colc] + bhh[g * 128 + colc];
#pragma unroll
    for (int m = 0; m < 4; m++)
#pragma unroll
        for (int rr = 0; rr < 4; rr++) {
            int gr = rb + wr * 64 + m * 16 + lg * 4 + rr;
            if (gr >= M) continue;
            float gi = acc[m][0][rr] + bs4[0];
            float gf = acc[m][1][rr] + bs4[1];
            float gg = acc[m][2][rr] + bs4[2];
            float go = acc[m][3][rr] + bs4[3];
            size_t p = (size_t)gr * 128 + colc;
            float cold = c_st[p];
            float cn = sigf(gf) * cold + sigf(gi) * tanhf(gg);
            float hn = sigf(go) * tanhf(cn);
            c_st[p] = cn;
            h_out[p] = hn;
        }
}

extern "C" void kernel_launch(void* const* d_in, const int* in_sizes, int n_in,
                              void* d_out, int out_size, void* d_ws, size_t ws_size,
                              hipStream_t stream)
{
    const float* l_pos   = (const float*)d_in[0];
    const float* l_neg   = (const float*)d_in[1];
    const float* c_emb   = (const float*)d_in[2];
    const float* l_mlp_W = (const float*)d_in[3];
    const float* l_mlp_b = (const float*)d_in[4];
    const float* c_mlp_W = (const float*)d_in[5];
    const float* c_mlp_b = (const float*)d_in[6];
    const float* l_Wih   = (const float*)d_in[7];
    const float* l_Whh   = (const float*)d_in[8];
    const float* l_bih   = (const float*)d_in[9];
    const float* l_bhh   = (const float*)d_in[10];
    const float* c_Wih   = (const float*)d_in[11];
    const float* c_Whh   = (const float*)d_in[12];
    const float* c_bih   = (const float*)d_in[13];
    const float* c_bhh   = (const float*)d_in[14];
    const int* pos_src   = (const int*)d_in[15];
    const int* pos_dst   = (const int*)d_in[16];
    const int* neg_src   = (const int*)d_in[17];
    const int* neg_dst   = (const int*)d_in[18];

    float* out  = (float*)d_out;
    float* l_hA = out;
    float* c_hP = out + (size_t)NL * 128;     // clause-h ping (final resting place)

    float* wsp = (float*)d_ws;
    float* l_hB  = wsp; wsp += (size_t)NL * 128;
    float* l_c   = wsp; wsp += (size_t)NL * 128;
    float* c_c   = wsp; wsp += (size_t)NC * 128;
    float* l_msg = wsp; wsp += (size_t)NL * 128;
    float* c_hQ  = wsp; wsp += (size_t)NC * 128;   // clause-h pong / doubles as c_msg buffer
    float* l2c   = wsp; wsp += (size_t)NC * 128;
    float* c2l = l_msg;  // gather #2 writes here after gather #1 consumed l_msg

    unsigned short* us = (unsigned short*)wsp;
    unsigned short* mlpLh = us; us += 3 * 128 * 128;
    unsigned short* mlpLl = us; us += 3 * 128 * 128;
    unsigned short* mlpCh = us; us += 3 * 128 * 128;
    unsigned short* mlpCl = us; us += 3 * 128 * 128;
    unsigned short* lstmLh = us; us += 512 * 384;
    unsigned short* lstmLl = us; us += 512 * 384;
    unsigned short* lstmCh = us; us += 512 * 256;
    unsigned short* lstmCl = us; us += 512 * 256;

    int* ip = (int*)us;
    int* cnt_c    = ip; ip += NC;
    int* rowptr_c = ip; ip += NC + 1;
    int* cur_c    = ip; ip += NC;
    int* eidx_c   = ip; ip += 2 * NE;
    int* cnt_l    = ip; ip += NL;
    int* rowptr_l = ip; ip += NL + 1;
    int* cur_l    = ip; ip += NL;
    int* eidx_l   = ip; ip += 2 * NE;
    int* part_c   = ip; ip += 256;
    int* part_l   = ip; ip += 256;

    // init states
    hipMemcpyAsync(l_hA, l_pos, (size_t)NV * 128 * 4, hipMemcpyDeviceToDevice, stream);
    hipMemcpyAsync(l_hA + (size_t)NV * 128, l_neg, (size_t)NV * 128 * 4, hipMemcpyDeviceToDevice, stream);
    hipMemcpyAsync(c_hP, c_emb, (size_t)NC * 128 * 4, hipMemcpyDeviceToDevice, stream);
    hipMemsetAsync(l_c, 0, (size_t)NL * 128 * 4, stream);
    hipMemsetAsync(c_c, 0, (size_t)NC * 128 * 4, stream);

    // pack weights (once per call)
    pack_mlp_frag<<<24, 256, 0, stream>>>(l_mlp_W, mlpLh, mlpLl);
    pack_mlp_frag<<<24, 256, 0, stream>>>(c_mlp_W, mlpCh, mlpCl);
    pack_lstm_frag<<<96, 256, 0, stream>>>(l_Wih, l_Whh, 256, 12, lstmLh, lstmLl);
    pack_lstm_frag<<<64, 256, 0, stream>>>(c_Wih, c_Whh, 128, 8, lstmCh, lstmCl);

    // ---- CSR build (once per call; graph static across rounds) ----
    hipMemsetAsync(cnt_c, 0, NC * sizeof(int), stream);
    hipMemsetAsync(cnt_l, 0, NL * sizeof(int), stream);
    constexpr int EB = (NE + 255) / 256;
    csr_hist_k<<<EB, 256, 0, stream>>>(pos_src, pos_dst, neg_src, neg_dst, cnt_c, cnt_l);
    constexpr int NBC = (NC + 1023) / 1024;
    constexpr int NBL = (NL + 1023) / 1024;
    scan_p1<<<NBC, 256, 0, stream>>>(cnt_c, part_c, NC);
    scan_p2<<<1, 256, 0, stream>>>(part_c, NBC, rowptr_c + NC);
    scan_p3<<<NBC, 256, 0, stream>>>(cnt_c, part_c, rowptr_c, cur_c, NC);
    scan_p1<<<NBL, 256, 0, stream>>>(cnt_l, part_l, NL);
    scan_p2<<<1, 256, 0, stream>>>(part_l, NBL, rowptr_l + NL);
    scan_p3<<<NBL, 256, 0, stream>>>(cnt_l, part_l, rowptr_l, cur_l, NL);
    csr_fill_k<<<EB, 256, 0, stream>>>(pos_src, pos_dst, neg_src, neg_dst,
                                       cur_c, eidx_c, cur_l, eidx_l);

    float* l_cur = l_hA;
    float* l_nxt = l_hB;
    float* c_cur = c_hP;
    float* c_oth = c_hQ;

    for (int r = 0; r < NROUNDS; r++) {
        // MLPs: l_cur -> l_msg ; c_cur -> c_oth (c_msg lives in the dead clause-h buffer)
        mlp3_v4<<<(NL + 63) / 64, 256, 0, stream>>>(l_cur, mlpLh, mlpLl, l_mlp_b, l_msg, NL);
        mlp3_v4<<<(NC + 63) / 64, 256, 0, stream>>>(c_cur, mlpCh, mlpCl, c_mlp_b, c_oth, NC);

        // gathers: l2c from l_msg ; c2l (aliases l_msg) from c_oth
        gather_sum_k<<<NC * 64 / 256, 256, 0, stream>>>(l_msg, rowptr_c, eidx_c, l2c, NC);
        gather_sum_k<<<NL * 64 / 256, 256, 0, stream>>>(c_oth, rowptr_l, eidx_l, c2l, NL);

        // literal LSTM: x = [c2l | flip(l_cur) | l_cur] -> l_nxt (l_c in place)
        lstm_v5<12, true><<<dim3(4, (NL + 127) / 128), 256, 0, stream>>>(
            c2l, l_cur, l_cur, lstmLh, lstmLl, l_bih, l_bhh, l_c, l_nxt, NL);
        // clause LSTM: x = [l2c | c_cur] -> h into c_oth (c_msg already consumed; c_c in place)
        lstm_v5<8, false><<<dim3(4, (NC + 127) / 128), 256, 0, stream>>>(
            l2c, c_cur, nullptr, lstmCh, lstmCl, c_bih, c_bhh, c_c, c_oth, NC);

        float* t2 = l_cur; l_cur = l_nxt; l_nxt = t2;
        t2 = c_cur; c_cur = c_oth; c_oth = t2;
    }
    // 26 even rounds: l_cur == l_hA (d_out), c_cur == c_hP (d_out).
    (void)in_sizes; (void)n_in; (void)out_size; (void)ws_size;
}